// Round 4
// baseline (109.968 us; speedup 1.0000x reference)
//
#include <hip/hip_runtime.h>

typedef unsigned short u16;
typedef __bf16 bf16x8 __attribute__((ext_vector_type(8)));
typedef float  f32x4  __attribute__((ext_vector_type(4)));

#define NEDGES 65536
#define NNODES 8192
#define EPB 32             // edges per block

#define PW0f       0.14433756729740643f   // (1/48)^0.5
#define PW1f       0.21650635094610965f   // (3/64)^0.5
#define INV_SQRT3f 0.5773502691896258f
#define INV_SQRT6f 0.4082482904638631f
#define SILU_NORMf 1.6790425f

// workspace layout (bf16 elements)
#define WT2_OFF 0          // [2560][64]  Wfc2^T, 0.125*region scale folded
#define WT0_OFF 163840     // [64][64]    Wfc0^T * 0.125
#define WT1_OFF 167936     // [64][64]    Wfc1^T * 0.125
#define WS_ELEMS 172032

#define HSTR 72            // padded bf16 row stride for h0/h1 LDS tiles

__device__ __forceinline__ float silu_n(float z) {
    return SILU_NORMf * z / (1.0f + __expf(-z));
}
__device__ __forceinline__ u16 f2bf(float f) {
    return __builtin_bit_cast(u16, (__bf16)f);
}
__device__ __forceinline__ float bf2f(u16 u) {
    unsigned v = ((unsigned)u) << 16;
    return __builtin_bit_cast(float, v);
}
__device__ __forceinline__ bf16x8 ld_bf8(const u16* p) {
    return *reinterpret_cast<const bf16x8*>(p);
}
__device__ __forceinline__ bf16x8 cvt_bf8(const float* p) {
    float4 a = *reinterpret_cast<const float4*>(p);
    float4 b = *reinterpret_cast<const float4*>(p + 4);
    bf16x8 r;
    r[0]=(__bf16)a.x; r[1]=(__bf16)a.y; r[2]=(__bf16)a.z; r[3]=(__bf16)a.w;
    r[4]=(__bf16)b.x; r[5]=(__bf16)b.y; r[6]=(__bf16)b.z; r[7]=(__bf16)b.w;
    return r;
}
#define MFMA16(A,B,C) __builtin_amdgcn_mfma_f32_16x16x32_bf16(A,B,C,0,0,0)

// ---------------------------------------------------------------------------
// Prep kernel (fused): blocks [0,672) transpose+scale+bf16 the MLP weights
// into d_ws; blocks [672,3232) compute the self-connection into d_out
// (re-initializes d_out every call).
// ---------------------------------------------------------------------------
__global__ void k_prep(const float* __restrict__ Wfc0,
                       const float* __restrict__ Wfc1,
                       const float* __restrict__ Wfc2,
                       const float* __restrict__ node_feat,
                       const float* __restrict__ Wsc0,
                       const float* __restrict__ Wsc1,
                       u16* __restrict__ ws,
                       float* __restrict__ out)
{
    const int bid = blockIdx.x;
    if (bid < 672) {
        int gid = bid * 256 + threadIdx.x;
        if (gid < 163840) {                 // gid = k*2560 + j (read-coalesced)
            int k = gid / 2560;
            int j = gid - k * 2560;
            float s;
            if (j < 1024)      s = PW0f;
            else if (j < 1536) s = PW0f * INV_SQRT3f;
            else if (j < 2304) s = PW1f * INV_SQRT3f;
            else               s = PW1f * INV_SQRT6f;
            ws[WT2_OFF + j * 64 + k] = f2bf(Wfc2[gid] * (0.125f * s));
        } else if (gid < WT1_OFF) {
            int i = gid - WT0_OFF;
            int k = i >> 6, n = i & 63;
            ws[WT0_OFF + n * 64 + k] = f2bf(Wfc0[i] * 0.125f);
        } else if (gid < WS_ELEMS) {
            int i = gid - WT1_OFF;
            int k = i >> 6, n = i & 63;
            ws[WT1_OFF + n * 64 + k] = f2bf(Wfc1[i] * 0.125f);
        }
    } else {
        int gid = (bid - 672) * 256 + threadIdx.x;
        if (gid >= NNODES * 80) return;
        int n = gid / 80;
        int s = gid - n * 80;
        const float* nf = node_feat + (size_t)n * 80;
        float r;
        if (s < 32) {
            float a = 0.f;
            #pragma unroll
            for (int u = 0; u < 32; ++u) a += nf[u] * Wsc0[u * 32 + s];
            r = a * 0.17677669529663687f;   // 1/sqrt(32)
        } else {
            int v = (s - 32) / 3;
            int k = (s - 32) - v * 3;
            float a = 0.f;
            #pragma unroll
            for (int u = 0; u < 16; ++u) a += nf[32 + u * 3 + k] * Wsc1[u * 16 + v];
            r = a * 0.25f;                   // 1/sqrt(16)
        }
        out[gid] = r;
    }
}

// ---------------------------------------------------------------------------
// Main fused kernel: 32 edges / block, 4 waves, 2048 blocks.
// Phase 1 (concurrent, disjoint LDS):
//   waves 0,1: fc0+fc1 MFMA for 16 edges each -> h1S
//   waves 2,3: left-factor tables (c12S = x0*y0 | dot; x0S = raw x0;
//              cw45 = x1*y0 | cross; y1S, dstS)
// Main loop (roles rotated per block, cost-balanced ~1920 cyc each):
//   role0: tiles [0,48)    W1            -> acc0 (16 regs)
//   role1: tiles [48,96)   W1+W2         -> acc0
//   role2: tiles [96,136)  W3(factored: s=Sum_u x0[u]*d) + W4 u0..7 -> accS+accB
//   role3: tiles [136,160) W4 u8..15 + W5 -> accB (24 regs)
// W3's outer product with y1 applied once at reduce time.
// ---------------------------------------------------------------------------
__global__ __launch_bounds__(256, 4) void k_main(
    const int*   __restrict__ eidx,
    const float* __restrict__ node_feat,
    const float* __restrict__ edge_feat,
    const float* __restrict__ edge_embed,
    const u16*   __restrict__ ws,
    float*       __restrict__ out)
{
    __shared__ __align__(16) char smem[20992];
    u16*   h1S  = (u16*)(smem);             // [32][72] 4608 B (persistent)
    u16*   h0S  = (u16*)(smem + 4608);      // [32][72] 4608 B (fc only)
    u16*   c12S = (u16*)(smem + 9216);      // [48][32] 3072 B (u<32: x0*y0, u>=32: dot)
    u16*   x0S  = (u16*)(smem + 12288);     // [32][32] 2048 B (raw x0)
    u16*   cw45 = (u16*)(smem + 14336);     // [96][32] 6144 B (x1*y0 rows 0..47, cross 48..95)
    float* y1S  = (float*)(smem + 20480);   // [3][32]  384 B
    int*   dstS = (int*)(smem + 20864);     // [32]     128 B
    float* msgS = (float*)(smem + 4608);    // alias: [32][81] f32 = 10368 B (reduce phase)

    const int t    = threadIdx.x;
    const int lane = t & 63;
    const int l15  = lane & 15;
    const int lq   = lane >> 4;
    const int wid  = t >> 6;
    const int role = (wid + blockIdx.x) & 3;
    const int eg0  = blockIdx.x * EPB;

    const u16* WT2 = ws + WT2_OFF;

    if (wid < 2) {
        // ---------------- fc0/fc1 for this wave's 16 edges -----------------
        const u16* WT0 = ws + WT0_OFF;
        const u16* WT1 = ws + WT1_OFF;
        const float* erow = edge_embed + (size_t)(eg0 + wid * 16 + l15) * 64 + 8 * lq;
        bf16x8 eB0 = cvt_bf8(erow);
        bf16x8 eB1 = cvt_bf8(erow + 32);
        #pragma unroll
        for (int ntl = 0; ntl < 4; ++ntl) {
            const u16* a = WT0 + (ntl * 16 + l15) * 64 + 8 * lq;
            bf16x8 A0 = ld_bf8(a);
            bf16x8 A1 = ld_bf8(a + 32);
            f32x4 z = {0.f, 0.f, 0.f, 0.f};
            z = MFMA16(A0, eB0, z);
            f32x4 dd = MFMA16(A1, eB1, z);
            ushort4 pk;
            pk.x = f2bf(silu_n(dd[0]));
            pk.y = f2bf(silu_n(dd[1]));
            pk.z = f2bf(silu_n(dd[2]));
            pk.w = f2bf(silu_n(dd[3]));
            *(ushort4*)&h0S[(wid * 16 + l15) * HSTR + ntl * 16 + lq * 4] = pk;
        }
        const u16* hrow = h0S + (wid * 16 + l15) * HSTR + 8 * lq;
        bf16x8 hB0 = ld_bf8(hrow);
        bf16x8 hB1 = ld_bf8(hrow + 32);
        #pragma unroll
        for (int ntl = 0; ntl < 4; ++ntl) {
            const u16* a = WT1 + (ntl * 16 + l15) * 64 + 8 * lq;
            bf16x8 A0 = ld_bf8(a);
            bf16x8 A1 = ld_bf8(a + 32);
            f32x4 z = {0.f, 0.f, 0.f, 0.f};
            z = MFMA16(A0, hB0, z);
            f32x4 dd = MFMA16(A1, hB1, z);
            ushort4 pk;
            pk.x = f2bf(silu_n(dd[0]));
            pk.y = f2bf(silu_n(dd[1]));
            pk.z = f2bf(silu_n(dd[2]));
            pk.w = f2bf(silu_n(dd[3]));
            *(ushort4*)&h1S[(wid * 16 + l15) * HSTR + ntl * 16 + lq * 4] = pk;
        }
    } else {
        // ---------------- left-factor tables, 4 threads per edge -----------
        const int t2  = t - 128;
        const int e   = t2 & 31;
        const int q   = t2 >> 5;
        const int eg  = eg0 + e;
        const int src = eidx[eg];
        const float* nf = node_feat + (size_t)src * 80;
        const float* ef = edge_feat + (size_t)eg * 4;
        if (q == 0) {
            dstS[e] = eidx[NEDGES + eg];
            const float y0 = ef[0];
            y1S[e] = ef[1]; y1S[32 + e] = ef[2]; y1S[64 + e] = ef[3];
            #pragma unroll
            for (int u = 0; u < 32; ++u) c12S[u * 32 + e] = f2bf(nf[u] * y0);
        } else if (q == 1) {
            const float ya = ef[1], yb = ef[2], yc = ef[3];
            #pragma unroll
            for (int u = 0; u < 16; ++u) {
                float d = nf[32 + u * 3] * ya + nf[32 + u * 3 + 1] * yb
                        + nf[32 + u * 3 + 2] * yc;
                c12S[(32 + u) * 32 + e] = f2bf(d);
            }
            #pragma unroll
            for (int u = 0; u < 32; ++u) x0S[u * 32 + e] = f2bf(nf[u]);
        } else if (q == 2) {
            const float y0 = ef[0];
            #pragma unroll
            for (int u = 0; u < 16; ++u) {
                cw45[(u * 3 + 0) * 32 + e] = f2bf(nf[32 + u * 3 + 0] * y0);
                cw45[(u * 3 + 1) * 32 + e] = f2bf(nf[32 + u * 3 + 1] * y0);
                cw45[(u * 3 + 2) * 32 + e] = f2bf(nf[32 + u * 3 + 2] * y0);
            }
        } else {
            const float ya = ef[1], yb = ef[2], yc = ef[3];
            #pragma unroll
            for (int u = 0; u < 16; ++u) {
                const float xa = nf[32 + u * 3], xb = nf[32 + u * 3 + 1], xc = nf[32 + u * 3 + 2];
                cw45[(48 + u * 3 + 0) * 32 + e] = f2bf(xb * yc - xc * yb);
                cw45[(48 + u * 3 + 1) * 32 + e] = f2bf(xc * ya - xa * yc);
                cw45[(48 + u * 3 + 2) * 32 + e] = f2bf(xa * yb - xb * ya);
            }
        }
    }
    __syncthreads();

    // ---------------- B fragments (32 edges = 2 eg groups) -----------------
    bf16x8 hb[2][2];
    #pragma unroll
    for (int eg = 0; eg < 2; ++eg) {
        const u16* r = h1S + (eg * 16 + l15) * HSTR + 8 * lq;
        hb[eg][0] = ld_bf8(r);
        hb[eg][1] = ld_bf8(r + 32);
    }

    // acc layout: roles 0/1: acc[eg*8+hs*4+r] (16 used)
    //             role 2:   accB acc[eg*12+r*3+k] (24) + accS acc[24+eg*4+r] (8)
    //             role 3:   accB acc[eg*12+r*3+k] (24)
    float acc[32];
    #pragma unroll
    for (int i = 0; i < 32; ++i) acc[i] = 0.f;

    int t0, ntile;
    if      (role == 0) { t0 = 0;   ntile = 48; }
    else if (role == 1) { t0 = 48;  ntile = 48; }
    else if (role == 2) { t0 = 96;  ntile = 40; }   // W3 (32) + W4 u0..7 (8)
    else                { t0 = 136; ntile = 24; }   // W4 u8..15 (8) + W5 (16)

    const u16* Aw = WT2 + l15 * 64 + 8 * lq;   // +1024 elems per tile

#define COMPUTE(A0_, A1_, D_)                                          \
    {                                                                  \
        _Pragma("unroll")                                              \
        for (int eg = 0; eg < 2; ++eg) {                               \
            f32x4 z = {0.f, 0.f, 0.f, 0.f};                            \
            z = MFMA16(A0_, hb[eg][0], z);                             \
            D_[eg] = MFMA16(A1_, hb[eg][1], z);                        \
        }                                                              \
    }

    // HS_ = compile-time tile parity (tt&1) for the msg0 acc index
#define EPILOGUE(D_, TT_, HS_)                                               \
    {                                                                        \
        if ((TT_) < 96) {                   /* W1/W2 -> msg0 partial */      \
            const u16* cr = c12S + ((TT_) >> 1) * 32;                        \
            _Pragma("unroll")                                                \
            for (int eg = 0; eg < 2; ++eg) {                                 \
                const float c = bf2f(cr[eg * 16 + l15]);                     \
                _Pragma("unroll")                                            \
                for (int r = 0; r < 4; ++r)                                  \
                    acc[eg * 8 + (HS_) * 4 + r] += c * D_[eg][r];            \
            }                                                                \
        } else if ((TT_) < 128) {           /* W3 factored: s += x0[u]*d */  \
            const u16* cr = x0S + ((TT_) - 96) * 32;                         \
            _Pragma("unroll")                                                \
            for (int eg = 0; eg < 2; ++eg) {                                 \
                const float c = bf2f(cr[eg * 16 + l15]);                     \
                _Pragma("unroll")                                            \
                for (int r = 0; r < 4; ++r)                                  \
                    acc[24 + eg * 4 + r] += c * D_[eg][r];                   \
            }                                                                \
        } else {                            /* W4/W5 -> msg1 direct */       \
            const u16* cr = cw45 + ((TT_) - 128) * 96;                       \
            _Pragma("unroll")                                                \
            for (int eg = 0; eg < 2; ++eg) {                                 \
                const int e16 = eg * 16 + l15;                               \
                const float c0 = bf2f(cr[e16]);                              \
                const float c1 = bf2f(cr[32 + e16]);                         \
                const float c2 = bf2f(cr[64 + e16]);                         \
                _Pragma("unroll")                                            \
                for (int r = 0; r < 4; ++r) {                                \
                    const float dv = D_[eg][r];                              \
                    acc[eg * 12 + r * 3 + 0] += c0 * dv;                     \
                    acc[eg * 12 + r * 3 + 1] += c1 * dv;                     \
                    acc[eg * 12 + r * 3 + 2] += c2 * dv;                     \
                }                                                            \
            }                                                                \
        }                                                                    \
    }

    // ---------------- main fc2 loop: 2-stage pipeline ----------------------
    bf16x8 Aa0, Aa1, Ab0, Ab1;
    {
        const u16* p = Aw + (size_t)t0 * 1024;
        Aa0 = ld_bf8(p); Aa1 = ld_bf8(p + 32);
        const u16* q = Aw + (size_t)(t0 + 1) * 1024;
        Ab0 = ld_bf8(q); Ab1 = ld_bf8(q + 32);
    }
    const int np = ntile >> 1;
    #pragma unroll 1
    for (int p = 0; p < np; ++p) {
        const int tt = t0 + 2 * p;
        bf16x8 Ac0, Ac1, Ad0, Ad1;
        const bool more = (p + 1 < np);
        if (more) {
            const u16* q = Aw + (size_t)(tt + 2) * 1024;
            Ac0 = ld_bf8(q); Ac1 = ld_bf8(q + 32);
        }
        f32x4 d[2];
        COMPUTE(Aa0, Aa1, d);
        EPILOGUE(d, tt, 0);
        if (more) {
            const u16* q = Aw + (size_t)(tt + 3) * 1024;
            Ad0 = ld_bf8(q); Ad1 = ld_bf8(q + 32);
        }
        COMPUTE(Ab0, Ab1, d);
        EPILOGUE(d, tt + 1, 1);
        if (more) { Aa0 = Ac0; Aa1 = Ac1; Ab0 = Ad0; Ab1 = Ad1; }
    }
#undef COMPUTE
#undef EPILOGUE

    // ---------------- cross-wave reduce (owner-ordered, no atomics) --------
    __syncthreads();   // everyone done reading coef tables; msgS aliases them
    if (role == 0) {
        #pragma unroll
        for (int eg = 0; eg < 2; ++eg) {
            float* mb = msgS + (eg * 16 + l15) * 81;
            #pragma unroll
            for (int hs = 0; hs < 2; ++hs)
                #pragma unroll
                for (int r = 0; r < 4; ++r)
                    mb[hs * 16 + lq * 4 + r] = acc[eg * 8 + hs * 4 + r];
        }
    } else if (role == 2) {
        // msg1 = W4-partial + (W3 s-vector) outer y1
        #pragma unroll
        for (int eg = 0; eg < 2; ++eg) {
            const int e = eg * 16 + l15;
            const float w1x = y1S[e], w1y = y1S[32 + e], w1z = y1S[64 + e];
            float* mb = msgS + e * 81 + 32;
            #pragma unroll
            for (int r = 0; r < 4; ++r) {
                const float s = acc[24 + eg * 4 + r];
                mb[(lq * 4 + r) * 3 + 0] = acc[eg * 12 + r * 3 + 0] + s * w1x;
                mb[(lq * 4 + r) * 3 + 1] = acc[eg * 12 + r * 3 + 1] + s * w1y;
                mb[(lq * 4 + r) * 3 + 2] = acc[eg * 12 + r * 3 + 2] + s * w1z;
            }
        }
    }
    __syncthreads();
    if (role == 1) {
        #pragma unroll
        for (int eg = 0; eg < 2; ++eg) {
            float* mb = msgS + (eg * 16 + l15) * 81;
            #pragma unroll
            for (int hs = 0; hs < 2; ++hs)
                #pragma unroll
                for (int r = 0; r < 4; ++r)
                    mb[hs * 16 + lq * 4 + r] += acc[eg * 8 + hs * 4 + r];
        }
    } else if (role == 3) {
        #pragma unroll
        for (int eg = 0; eg < 2; ++eg) {
            float* mb = msgS + (eg * 16 + l15) * 81 + 32;
            #pragma unroll
            for (int r = 0; r < 4; ++r)
                #pragma unroll
                for (int k = 0; k < 3; ++k)
                    mb[(lq * 4 + r) * 3 + k] += acc[eg * 12 + r * 3 + k];
        }
    }
    __syncthreads();

    // ---------------- global scatter ---------------------------------------
    for (int idx = t; idx < EPB * 80; idx += 256) {
        const int e = idx / 80;
        const int s = idx - e * 80;
        atomicAdd(out + (size_t)dstS[e] * 80 + s, msgS[e * 81 + s]);
    }
}

extern "C" void kernel_launch(void* const* d_in, const int* in_sizes, int n_in,
                              void* d_out, int out_size, void* d_ws, size_t ws_size,
                              hipStream_t stream) {
    const int*   eidx       = (const int*)d_in[0];
    const float* node_feat  = (const float*)d_in[1];
    const float* edge_feat  = (const float*)d_in[2];
    const float* edge_embed = (const float*)d_in[3];
    const float* Wfc0       = (const float*)d_in[5];
    const float* Wfc1       = (const float*)d_in[6];
    const float* Wfc2       = (const float*)d_in[7];
    const float* Wsc0       = (const float*)d_in[8];
    const float* Wsc1       = (const float*)d_in[9];
    float* out = (float*)d_out;
    u16*   ws  = (u16*)d_ws;

    if (ws_size < (size_t)WS_ELEMS * sizeof(u16)) return;  // need 344 KB scratch

    hipLaunchKernelGGL(k_prep, dim3(672 + 2560), dim3(256), 0, stream,
                       Wfc0, Wfc1, Wfc2, node_feat, Wsc0, Wsc1, ws, out);
    hipLaunchKernelGGL(k_main, dim3(NEDGES / EPB), dim3(256), 0, stream,
                       eidx, node_feat, edge_feat, edge_embed, ws, out);
}